// Round 1
// baseline (1610.231 us; speedup 1.0000x reference)
//
#include <hip/hip_runtime.h>
#include <math.h>

// Problem constants (reference: B,T,D=16,512,256; HS=512, D_A=64, R=8)
#define BB 16
#define TT 512
#define DD 256
#define HS 512
#define DA 64
#define RR 8
#define G4H 2048   // 4*HS

// -------- workspace layout (float offsets) --------
// s     :        0  (B*T*R =  65536)  <- k5's hbuf64 overlays this (dead by k4)
// e     :    65536
// inv   :   131072
// M     :   196608  (B*T*D   = 2097152)
// gates :  2293760  (B*T*4H  = 16777216)

// ============================================================
// K1: s[b,t,r] = tanh(x[b,t,:] @ w1 + b1) @ w2 + b2
// ============================================================
__global__ __launch_bounds__(256) void k1_score(
    const float* __restrict__ x, const float* __restrict__ w1,
    const float* __restrict__ b1, const float* __restrict__ w2,
    const float* __restrict__ b2, float* __restrict__ s_out) {
  const int wave = threadIdx.x >> 6;
  const int lane = threadIdx.x & 63;
  for (int i = 0; i < 4; ++i) {
    const int bt = blockIdx.x * 16 + wave * 4 + i;  // grid=512 -> 8192 bt
    const float* xr = x + bt * DD;
    float acc = b1[lane];
    #pragma unroll 4
    for (int d = 0; d < DD; ++d)
      acc = fmaf(xr[d], w1[d * DA + lane], acc);   // w1 coalesced over lanes
    const float a = tanhf(acc);
    #pragma unroll
    for (int r = 0; r < RR; ++r) {
      float v = a * w2[lane * RR + r];
      for (int off = 32; off > 0; off >>= 1) v += __shfl_xor(v, off);
      if (lane == 0) s_out[bt * RR + r] = v + b2[r];
    }
  }
}

// ============================================================
// K2: per (b,r): m=max_t s; e=exp(s-m); den=inclusive prefix sum
// ============================================================
__global__ __launch_bounds__(512) void k2_prefix(
    const float* __restrict__ s_in, float* __restrict__ e_out,
    float* __restrict__ inv_out) {
  const int b = blockIdx.x >> 3, r = blockIdx.x & 7;
  const int t = threadIdx.x;
  __shared__ float red[TT];
  __shared__ float buf[2][TT];
  const float v = s_in[(b * TT + t) * RR + r];
  red[t] = v;
  __syncthreads();
  for (int off = 256; off >= 1; off >>= 1) {
    if (t < off) red[t] = fmaxf(red[t], red[t + off]);
    __syncthreads();
  }
  const float m = red[0];
  const float e = expf(v - m);
  int p = 0;
  buf[0][t] = e;
  __syncthreads();
  for (int off = 1; off < TT; off <<= 1) {
    const float add = (t >= off) ? buf[p][t - off] : 0.f;
    buf[1 - p][t] = buf[p][t] + add;
    __syncthreads();
    p ^= 1;
  }
  const float den = buf[p][t];
  e_out[(b * TT + t) * RR + r] = e;
  inv_out[(b * TT + t) * RR + r] = 1.0f / den;
}

// ============================================================
// K3: M[b,t,d] = (1/R) * sum_r inv[t,r] * prefix_j<=t( e[j,r]*x[b,j,d] )
// ============================================================
__global__ __launch_bounds__(64) void k3_mix(
    const float* __restrict__ x, const float* __restrict__ e_in,
    const float* __restrict__ inv_in, float* __restrict__ Mout) {
  const int b = blockIdx.x >> 2;
  const int d = (blockIdx.x & 3) * 64 + threadIdx.x;
  __shared__ __align__(16) float el[TT * RR];
  __shared__ __align__(16) float il[TT * RR];
  for (int i = threadIdx.x * 4; i < TT * RR; i += 64 * 4) {
    *(float4*)&el[i] = *(const float4*)&e_in[b * TT * RR + i];
    *(float4*)&il[i] = *(const float4*)&inv_in[b * TT * RR + i];
  }
  __syncthreads();
  float4 c0 = {0.f, 0.f, 0.f, 0.f}, c1 = {0.f, 0.f, 0.f, 0.f};
  for (int t = 0; t < TT; ++t) {
    const float xv = x[(b * TT + t) * DD + d];
    const float4 e0 = *(const float4*)&el[t * RR];
    const float4 e1 = *(const float4*)&el[t * RR + 4];
    const float4 i0 = *(const float4*)&il[t * RR];
    const float4 i1 = *(const float4*)&il[t * RR + 4];
    c0.x = fmaf(e0.x, xv, c0.x); c0.y = fmaf(e0.y, xv, c0.y);
    c0.z = fmaf(e0.z, xv, c0.z); c0.w = fmaf(e0.w, xv, c0.w);
    c1.x = fmaf(e1.x, xv, c1.x); c1.y = fmaf(e1.y, xv, c1.y);
    c1.z = fmaf(e1.z, xv, c1.z); c1.w = fmaf(e1.w, xv, c1.w);
    float msum = c0.x * i0.x + c0.y * i0.y + c0.z * i0.z + c0.w * i0.w;
    msum += c1.x * i1.x + c1.y * i1.y + c1.z * i1.z + c1.w * i1.w;
    Mout[(b * TT + t) * DD + d] = msum * 0.125f;
  }
}

// ============================================================
// K4: gates = M(8192x256) @ W_ih(256x2048) + bias   (fp32 SGEMM)
// ============================================================
__global__ __launch_bounds__(256) void k4_gemm(
    const float* __restrict__ A, const float* __restrict__ Bw,
    const float* __restrict__ bias, float* __restrict__ C) {
  const int bn = blockIdx.x & 15;
  const int bm = blockIdx.x >> 4;
  const int tid = threadIdx.x;
  const int tx = tid & 15, ty = tid >> 4;
  __shared__ __align__(16) float As[16][132];
  __shared__ __align__(16) float Bs[16][132];
  const int row0 = bm * 128, col0 = bn * 128;

  float acc[2][4][2][4];
  #pragma unroll
  for (int a = 0; a < 2; ++a)
    #pragma unroll
    for (int i = 0; i < 4; ++i)
      #pragma unroll
      for (int q = 0; q < 2; ++q)
        #pragma unroll
        for (int j = 0; j < 4; ++j) acc[a][i][q][j] = 0.f;

  const int arow = tid >> 1, akc = (tid & 1) * 8;
  const int bkr = tid >> 4, bcc = (tid & 15) * 8;

  for (int k0 = 0; k0 < 256; k0 += 16) {
    const float4 a0 = *(const float4*)&A[(row0 + arow) * 256 + k0 + akc];
    const float4 a1 = *(const float4*)&A[(row0 + arow) * 256 + k0 + akc + 4];
    const float4 b0 = *(const float4*)&Bw[(k0 + bkr) * 2048 + col0 + bcc];
    const float4 b1 = *(const float4*)&Bw[(k0 + bkr) * 2048 + col0 + bcc + 4];
    __syncthreads();
    As[akc + 0][arow] = a0.x; As[akc + 1][arow] = a0.y;
    As[akc + 2][arow] = a0.z; As[akc + 3][arow] = a0.w;
    As[akc + 4][arow] = a1.x; As[akc + 5][arow] = a1.y;
    As[akc + 6][arow] = a1.z; As[akc + 7][arow] = a1.w;
    *(float4*)&Bs[bkr][bcc] = b0;
    *(float4*)&Bs[bkr][bcc + 4] = b1;
    __syncthreads();
    #pragma unroll
    for (int kk = 0; kk < 16; ++kk) {
      float av[8], bv[8];
      *(float4*)&av[0] = *(const float4*)&As[kk][ty * 4];
      *(float4*)&av[4] = *(const float4*)&As[kk][64 + ty * 4];
      *(float4*)&bv[0] = *(const float4*)&Bs[kk][tx * 4];
      *(float4*)&bv[4] = *(const float4*)&Bs[kk][64 + tx * 4];
      #pragma unroll
      for (int a = 0; a < 2; ++a)
        #pragma unroll
        for (int i = 0; i < 4; ++i)
          #pragma unroll
          for (int q = 0; q < 2; ++q)
            #pragma unroll
            for (int j = 0; j < 4; ++j)
              acc[a][i][q][j] = fmaf(av[a * 4 + i], bv[q * 4 + j], acc[a][i][q][j]);
    }
  }
  const float4 bias0 = *(const float4*)&bias[col0 + tx * 4];
  const float4 bias1 = *(const float4*)&bias[col0 + 64 + tx * 4];
  #pragma unroll
  for (int a = 0; a < 2; ++a)
    #pragma unroll
    for (int i = 0; i < 4; ++i) {
      const int row = row0 + a * 64 + ty * 4 + i;
      float4 v0, v1;
      v0.x = acc[a][i][0][0] + bias0.x; v0.y = acc[a][i][0][1] + bias0.y;
      v0.z = acc[a][i][0][2] + bias0.z; v0.w = acc[a][i][0][3] + bias0.w;
      v1.x = acc[a][i][1][0] + bias1.x; v1.y = acc[a][i][1][1] + bias1.y;
      v1.z = acc[a][i][1][2] + bias1.z; v1.w = acc[a][i][1][3] + bias1.w;
      *(float4*)&C[row * 2048 + col0 + tx * 4] = v0;
      *(float4*)&C[row * 2048 + col0 + 64 + tx * 4] = v1;
    }
}

#define FMA4(ACC, W4, HSC)                         \
  ACC.x = fmaf((W4).x, (HSC), ACC.x);              \
  ACC.y = fmaf((W4).y, (HSC), ACC.y);              \
  ACC.z = fmaf((W4).z, (HSC), ACC.z);              \
  ACC.w = fmaf((W4).w, (HSC), ACC.w);

// fast transcendentals: v_exp_f32 + v_rcp_f32 (~1e-6 err << 1.5e-2 tol)
__device__ __forceinline__ float fast_sigmoid(float x) {
  return __builtin_amdgcn_rcpf(1.f + __expf(-x));
}
__device__ __forceinline__ float fast_tanh(float x) {
  const float xc = fmaxf(x, -30.f);           // avoid inf*0 NaN
  const float e = __expf(-2.f * xc);
  return (1.f - e) * __builtin_amdgcn_rcpf(1.f + e);
}

#define HPOLL(Q) __hip_atomic_load((Q), __ATOMIC_RELAXED, __HIP_MEMORY_SCOPE_AGENT)

// ============================================================
// K5 v8: 16 per-batch domains x 16 blocks (32 units), 512 thr.
// Changes vs v7 (post-mortem of counters):
//  (1) VGPR pin: v7's VGPR_Count=88 with no scratch traffic => compiler
//      homed wr[32] (128 floats) in AGPRs (unified file) and issued
//      ~128 v_accvgpr_read per thread per step next to the 128 FMAs --
//      half the FMA-phase VALU ops (matches VALUBusy=32% @ 4214cy/step).
//      A per-iteration empty asm with "+v" constraints on all 128
//      components makes AGPR homing cost 2x128 copies/iter, forcing a
//      pure-VGPR allocation (~160 VGPR total, still 8 waves/CU <= 256).
//  (2) 4-deep rotating poll: v7's load->check->reload loop samples the
//      packet once per MALL round-trip (~1kcy). Four relaxed atomic
//      loads kept in flight (in-order vmcnt completion) check the line
//      every ~RT/4, cutting discovery latency by ~3RT/8 per step.
// ============================================================
__global__ __launch_bounds__(512, 1) void k5_lstm(
    const float* __restrict__ gates, const float* __restrict__ whh,
    float* __restrict__ out, unsigned long long* hbuf) {
  const int s   = blockIdx.x & 15;       // unit-slice
  const int b   = blockIdx.x >> 4;       // batch = sync domain
  const int tid = threadIdx.x;           // 512 threads
  const int kq  = tid & 15;              // k-chunk: k in [kq*32, kq*32+32)
  const int cq  = tid >> 4;              // unit offset 0..31
  const int j0  = s * 32;
  const int unit = j0 + cq;

  __shared__ __align__(16) float Wl[256 * 128];  // staging, 128 KB
  __shared__ __align__(16) float hl[2][576];     // parity; chunk*36+pos

  // ---- stage W slice (coalesced) and gather into registers ----
  // wr[kk] = (W[k][i-col], W[k][f-col], W[k][g-col], W[k][o-col]) of
  // THIS thread's unit, k = (kq&7)*32 + kk + 256*(kq>>3)-round.
  float4 wr[32];
  for (int rnd = 0; rnd < 2; ++rnd) {
    for (int i = tid * 4; i < 256 * 128; i += 512 * 4) {
      const int k = i >> 7, c = i & 127;   // Wl[k][c], c = gate*32 + uo
      *(float4*)&Wl[i] =
          *(const float4*)&whh[(rnd * 256 + k) * G4H + (c >> 5) * HS + j0 + (c & 31)];
    }
    __syncthreads();
    if ((kq >> 3) == rnd) {
      const int kb = (kq & 7) * 32;
      #pragma unroll
      for (int kk = 0; kk < 32; ++kk) {
        const int base = (kb + kk) * 128 + cq;
        wr[kk].x = *(volatile const float*)&Wl[base];
        wr[kk].y = *(volatile const float*)&Wl[base + 32];
        wr[kk].z = *(volatile const float*)&Wl[base + 64];
        wr[kk].w = *(volatile const float*)&Wl[base + 96];
      }
    }
    __syncthreads();
  }

  float c_reg = 0.f;   // cell state (lives in lanes kq==0; unit j0+cq)

  for (int t = 0; t < TT; ++t) {
    // (1) VGPR pin: "+v" each iteration -> AGPR homing would need
    // 256 copies/iter; allocator keeps wr register-resident in VGPRs.
    #pragma unroll
    for (int kk = 0; kk < 32; ++kk)
      asm volatile("" : "+v"(wr[kk].x), "+v"(wr[kk].y),
                        "+v"(wr[kk].z), "+v"(wr[kk].w));

    // gate-x prefetch: 4 dwords (i,f,g,o of my unit), in flight over poll
    float gi = 0.f, gf = 0.f, gg = 0.f, go = 0.f;
    if (kq == 0) {
      const float* gt = gates + ((long)b * TT + t) * G4H + unit;
      gi = gt[0]; gf = gt[HS]; gg = gt[2 * HS]; go = gt[3 * HS];
    }
    const int par = t & 1;
    if (t > 0) {
      // (2) self-validating 4-deep rotating poll of my unit's packet.
      // Tag >= t implies tag == t (tag t+2 would require OUR step-t
      // publish, which happens after this poll -- same proof as v7).
      const unsigned long long* hp =
          hbuf + (((t - 1) & 1) * BB + b) * HS + tid;
      const unsigned tt = (unsigned)t;
      unsigned long long q0, q1, q2, q3, pkt;
      q0 = HPOLL(hp); q1 = HPOLL(hp); q2 = HPOLL(hp); q3 = HPOLL(hp);
      for (;;) {
        if ((unsigned)(q0 >> 32) >= tt) { pkt = q0; break; }
        q0 = HPOLL(hp);
        if ((unsigned)(q1 >> 32) >= tt) { pkt = q1; break; }
        q1 = HPOLL(hp);
        if ((unsigned)(q2 >> 32) >= tt) { pkt = q2; break; }
        q2 = HPOLL(hp);
        if ((unsigned)(q3 >> 32) >= tt) { pkt = q3; break; }
        q3 = HPOLL(hp);
      }
      hl[par][(tid >> 5) * 36 + (tid & 31)] = __uint_as_float((unsigned)pkt);
    }
    __syncthreads();  // the ONE barrier: hl[par] complete
    float4 acc = {0.f, 0.f, 0.f, 0.f};
    if (t > 0) {
      const float* hb = &hl[par][kq * 36];
      #pragma unroll
      for (int i = 0; i < 8; ++i) {
        const float4 h4 = *(const float4*)(hb + i * 4);
        FMA4(acc, wr[i * 4 + 0], h4.x);
        FMA4(acc, wr[i * 4 + 1], h4.y);
        FMA4(acc, wr[i * 4 + 2], h4.z);
        FMA4(acc, wr[i * 4 + 3], h4.w);
      }
    }
    // butterfly over the 16 kq lanes (in-wave: group = 16 consecutive)
    #pragma unroll
    for (int off = 1; off <= 8; off <<= 1) {
      acc.x += __shfl_xor(acc.x, off); acc.y += __shfl_xor(acc.y, off);
      acc.z += __shfl_xor(acc.z, off); acc.w += __shfl_xor(acc.w, off);
    }
    // fused epilogue + publish: lane kq==0 has full (i,f,g,o) of unit
    if (kq == 0) {
      const float I = fast_sigmoid(acc.x + gi);
      const float F = fast_sigmoid(acc.y + gf);
      const float G = fast_tanh(acc.z + gg);
      const float O = fast_sigmoid(acc.w + go);
      c_reg = F * c_reg + I * G;
      const float h = O * fast_tanh(c_reg);
      const unsigned long long pkt =
          ((unsigned long long)(unsigned)(t + 1) << 32) |
          (unsigned long long)__float_as_uint(h);
      __hip_atomic_store(&hbuf[((t & 1) * BB + b) * HS + unit], pkt,
                         __ATOMIC_RELAXED, __HIP_MEMORY_SCOPE_AGENT);
      out[((long)b * TT + t) * HS + unit] = h;   // hidden_seq (post-publish)
      if (t == TT - 1) {
        out[(long)BB * TT * HS + b * HS + unit] = h;               // h_t
        out[(long)BB * TT * HS + BB * HS + b * HS + unit] = c_reg; // c_t
      }
    }
  }
}

// ============================================================
extern "C" void kernel_launch(void* const* d_in, const int* in_sizes, int n_in,
                              void* d_out, int out_size, void* d_ws,
                              size_t ws_size, hipStream_t stream) {
  const float* x    = (const float*)d_in[0];
  const float* w1   = (const float*)d_in[1];
  const float* b1   = (const float*)d_in[2];
  const float* w2   = (const float*)d_in[3];
  const float* b2   = (const float*)d_in[4];
  const float* wih  = (const float*)d_in[5];
  const float* whh  = (const float*)d_in[6];
  const float* bias = (const float*)d_in[7];
  float* out = (float*)d_out;

  float* ws = (float*)d_ws;
  float* s_buf  = ws;                    // 65536 floats; dead after k2
  float* e_buf  = ws + 65536;
  float* i_buf  = ws + 131072;
  float* M_buf  = ws + 196608;
  float* g_buf  = ws + 2293760;
  // hbuf64 overlays the s region (2*16*512 uint64 = 128 KB <= 256 KB)
  unsigned long long* hbuf64 = (unsigned long long*)ws;

  k1_score<<<512, 256, 0, stream>>>(x, w1, b1, w2, b2, s_buf);
  k2_prefix<<<BB * RR, 512, 0, stream>>>(s_buf, e_buf, i_buf);
  k3_mix<<<64, 64, 0, stream>>>(x, e_buf, i_buf, M_buf);
  k4_gemm<<<64 * 16, 256, 0, stream>>>(M_buf, wih, bias, g_buf);
  // zero the packet tags (ws re-poisoned 0xAA each call; 0xAAAAAAAA > any t
  // would instantly satisfy polls). Stream-ordered after k2's s_buf reads.
  hipMemsetAsync(hbuf64, 0, 2 * BB * HS * sizeof(unsigned long long), stream);
  k5_lstm<<<256, 512, 0, stream>>>(g_buf, whh, out, hbuf64);
}